// Round 4
// baseline (740.036 us; speedup 1.0000x reference)
//
#include <hip/hip_runtime.h>
#include <math.h>

#define Bc 8
#define Lc 4096
#define Hc 8
#define Dc 64
#define NCH 16             // equal-WORK chunks (sqrt-spaced causal boundaries)
#define VCH 16
#define VROWS (Lc / VCH)   // 256 rows per cumsum chunk

// equal-work causal chunk boundaries: b_c ~= L*(1-sqrt(1-c/16)), 64-aligned
__constant__ int c_cb[NCH + 1] =
    {0, 128, 256, 384, 576, 704, 832, 1024, 1216, 1408,
     1600, 1792, 2048, 2304, 2624, 3072, 4096};

// ---------------------------------------------------------------- helpers
template<int CTRL>
__device__ __forceinline__ float dpp_mov(float v) {
    return __int_as_float(__builtin_amdgcn_update_dpp(
        0, __float_as_int(v), CTRL, 0xF, 0xF, true));
}
template<int CTRL>
__device__ __forceinline__ float dpp_radd(float v) {
    return v + dpp_mov<CTRL>(v);
}
__device__ __forceinline__ float row16_sum(float p) {
    p = dpp_radd<0x128>(p); p = dpp_radd<0x124>(p);
    p = dpp_radd<0x122>(p); p = dpp_radd<0x121>(p);
    return p;
}
__device__ __forceinline__ float wmax64(float v) {
    v = fmaxf(v, dpp_mov<0x128>(v));
    v = fmaxf(v, dpp_mov<0x124>(v));
    v = fmaxf(v, dpp_mov<0x122>(v));
    v = fmaxf(v, dpp_mov<0x121>(v));
    v = fmaxf(v, __shfl_xor(v, 16, 64));
    return fmaxf(v, __shfl_xor(v, 32, 64));
}
__device__ __forceinline__ float wsum64(float v) {
    v = row16_sum(v);
    v += __shfl_xor(v, 16, 64);
    return v + __shfl_xor(v, 32, 64);
}
__device__ __forceinline__ unsigned short f2bf(float f) {  // RNE fp32->bf16
    unsigned int u = __float_as_uint(f);
    u += 0x7FFFu + ((u >> 16) & 1u);
    return (unsigned short)(u >> 16);
}
__device__ __forceinline__ float bf2f(unsigned short s) {
    return __uint_as_float(((unsigned int)s) << 16);
}
__device__ __forceinline__ float bflo(unsigned int u) { return __uint_as_float(u << 16); }
__device__ __forceinline__ float bfhi(unsigned int u) { return __uint_as_float(u & 0xFFFF0000u); }

// ---------------------------------------------------------------- kernel 1
template<int S>
__global__ __launch_bounds__(256) void k_meas_t(
    const float* __restrict__ Q, const float* __restrict__ K,
    const int* __restrict__ idx, float* __restrict__ M)
{
    constexpr int NIT = (S + 3) / 4;
    int b = blockIdx.z, h = blockIdx.y;
    int w = threadIdx.x >> 6, lane = threadIdx.x & 63;
    int q = blockIdx.x * 4 + w;
    int grp = lane >> 4, gl = lane & 15;

    const float4 qv = *(const float4*)(Q + (((size_t)b * Lc + q) * Hc + h) * Dc + gl * 4);
    const int* ip = idx + (size_t)q * S + grp;
    const float* Kb = K + ((size_t)b * Lc * Hc + h) * Dc + gl * 4;

    int rows[NIT];
    #pragma unroll
    for (int it = 0; it < NIT - 1; it++) rows[it] = ip[it * 4];
    {
        int s = 4 * (NIT - 1) + grp;
        rows[NIT - 1] = ip[(s < S) ? 4 * (NIT - 1) : (S - 1 - grp)];
    }

    float mloc = -INFINITY, sloc = 0.f;
    #pragma unroll
    for (int it = 0; it < NIT; it++) {
        const float4 kw = *(const float4*)(Kb + ((size_t)rows[it] << 9));
        float p = kw.x * qv.x + kw.y * qv.y + kw.z * qv.z + kw.w * qv.w;
        p = row16_sum(p);
        int s = it * 4 + grp;
        if (s < S) { mloc = fmaxf(mloc, p); sloc += p; }
    }
    mloc = fmaxf(mloc, __shfl_xor(mloc, 16, 64));
    mloc = fmaxf(mloc, __shfl_xor(mloc, 32, 64));
    sloc += __shfl_xor(sloc, 16, 64);
    sloc += __shfl_xor(sloc, 32, 64);

    if (lane == 0)
        M[((size_t)(b * Hc + h)) * Lc + q] = mloc - sloc * (1.0f / (float)Lc);
}

__global__ __launch_bounds__(256) void k_meas_dyn(
    const float* __restrict__ Q, const float* __restrict__ K,
    const int* __restrict__ idx, float* __restrict__ M, int S)
{
    int b = blockIdx.z, h = blockIdx.y;
    int w = threadIdx.x >> 6, lane = threadIdx.x & 63;
    int q = blockIdx.x * 4 + w;
    int grp = lane >> 4, gl = lane & 15;

    const float4 qv = *(const float4*)(Q + (((size_t)b * Lc + q) * Hc + h) * Dc + gl * 4);
    const int* ip = idx + (size_t)q * S;
    const float* Kb = K + ((size_t)b * Lc * Hc + h) * Dc + gl * 4;

    float mloc = -INFINITY, sloc = 0.f;
    int niter = (S + 3) >> 2;
    for (int it = 0; it < niter; it++) {
        int s = it * 4 + grp;
        int ii = s < S ? s : S - 1;
        int row = ip[ii];
        const float4 kw = *(const float4*)(Kb + ((size_t)row << 9));
        float p = kw.x * qv.x + kw.y * qv.y + kw.z * qv.z + kw.w * qv.w;
        p = row16_sum(p);
        if (s < S) { mloc = fmaxf(mloc, p); sloc += p; }
    }
    mloc = fmaxf(mloc, __shfl_xor(mloc, 16, 64));
    mloc = fmaxf(mloc, __shfl_xor(mloc, 32, 64));
    sloc += __shfl_xor(sloc, 16, 64);
    sloc += __shfl_xor(sloc, 32, 64);
    if (lane == 0)
        M[((size_t)(b * Hc + h)) * Lc + q] = mloc - sloc * (1.0f / (float)Lc);
}

// ---------------------------------------------------------------- kernel 2
// top-U selection, then sort indices ASCENDING (order irrelevant to the
// reference's scatter; gives attn2 sorted query lists for tight cutoffs).
__global__ __launch_bounds__(256) void k_topk(
    const float* __restrict__ M, int* __restrict__ top, int U)
{
    int bh = blockIdx.x;
    int tid = threadIdx.x;
    const float* m = M + (size_t)bh * Lc;

    unsigned long long key[16];
    #pragma unroll
    for (int j = 0; j < 16; j++) {
        int i = tid * 16 + j;
        unsigned int u = __float_as_uint(m[i]);
        u ^= (unsigned int)(((int)u >> 31)) | 0x80000000u;
        key[j] = ((unsigned long long)u << 32) | (unsigned int)i;
    }
    unsigned long long myb = key[0];
    #pragma unroll
    for (int j = 1; j < 16; j++) myb = key[j] > myb ? key[j] : myb;

    __shared__ unsigned long long swave[2][4];
    __shared__ int swin[256];

    for (int u = 0; u < U; u++) {
        unsigned long long wmax = myb;
        #pragma unroll
        for (int o = 32; o >= 1; o >>= 1) {
            unsigned long long t = __shfl_xor(wmax, o, 64);
            wmax = t > wmax ? t : wmax;
        }
        if ((tid & 63) == 0) swave[u & 1][tid >> 6] = wmax;
        __syncthreads();
        unsigned long long w0 = swave[u & 1][0], w1 = swave[u & 1][1];
        unsigned long long w2 = swave[u & 1][2], w3 = swave[u & 1][3];
        unsigned long long a = w0 > w1 ? w0 : w1;
        unsigned long long c = w2 > w3 ? w2 : w3;
        unsigned long long win = a > c ? a : c;
        int widx = (int)(win & 0xFFFFFFFFu);
        if (tid == 0) swin[u] = widx;
        if (tid == (widx >> 4)) {
            #pragma unroll
            for (int j = 0; j < 16; j++) if (j == (widx & 15)) key[j] = 0ull;
            unsigned long long b2 = key[0];
            #pragma unroll
            for (int j = 1; j < 16; j++) b2 = key[j] > b2 ? key[j] : b2;
            myb = b2;
        }
    }
    __syncthreads();
    for (int ph = 0; ph < U; ph++) {
        int i = 2 * tid + (ph & 1);
        if (i + 1 < U) {
            int a = swin[i], b2 = swin[i + 1];
            if (a > b2) { swin[i] = b2; swin[i + 1] = a; }
        }
        __syncthreads();
    }
    if (tid < U) top[(size_t)bh * U + tid] = swin[tid];
}

// ---------------------------------------------------------------- kernel 3a
__global__ __launch_bounds__(256) void k_vsum(
    const float* __restrict__ V, float* __restrict__ bsum)
{
    int b = blockIdx.z, h = blockIdx.y, c = blockIdx.x;
    int d = threadIdx.x & 63, g = threadIdx.x >> 6;
    __shared__ float part[4][64];
    float s = 0.f;
    int r0 = c * VROWS;
    for (int r = r0 + g; r < r0 + VROWS; r += 4)
        s += V[(((size_t)b * Lc + r) * Hc + h) * Dc + d];
    part[g][d] = s;
    __syncthreads();
    if (g == 0)
        bsum[(((size_t)(b * Hc + h)) * VCH + c) * 64 + d] =
            part[0][d] + part[1][d] + part[2][d] + part[3][d];
}

// ---------------------------------------------------------------- kernel 3b
__global__ __launch_bounds__(256) void k_scan(
    const float* __restrict__ V, const float* __restrict__ bsum,
    float* __restrict__ out)
{
    int b = blockIdx.z, h = blockIdx.y, c = blockIdx.x;
    int d = threadIdx.x & 63, g = threadIdx.x >> 6;
    int bh = b * Hc + h;
    __shared__ float gtot[4][64];
    __shared__ float goff[4][64];

    float base = 0.f;
    for (int cc = 0; cc < c; cc++)
        base += bsum[((size_t)bh * VCH + cc) * 64 + d];

    int gs = c * VROWS + g * 64;
    float gsum = 0.f;
    for (int r = gs; r < gs + 64; r++)
        gsum += V[(((size_t)b * Lc + r) * Hc + h) * Dc + d];
    gtot[g][d] = gsum;
    __syncthreads();
    if (g == 0) {
        float run = base;
        for (int gg = 0; gg < 4; gg++) { goff[gg][d] = run; run += gtot[gg][d]; }
    }
    __syncthreads();
    float run = goff[g][d];
    for (int r = gs; r < gs + 64; r++) {
        size_t o = (((size_t)b * Lc + r) * Hc + h) * Dc + d;
        run += V[o];
        out[o] = run;
    }
}

// ---------------------------------------------------------------- kernel 4
// flash attention over selected (globally sorted) queries.
// Grid (NCH=16, H, B) = 1024 blocks, 256 threads, LDS 50.4KB -> 3 blocks/CU.
// Reg double-buffered staging; defer-max softmax; per-lane l accumulation.
__global__ __launch_bounds__(256) void k_attn2(
    const float* __restrict__ Q, const float* __restrict__ K,
    const float* __restrict__ V, const int* __restrict__ top,
    unsigned short* __restrict__ Opart, float* __restrict__ Mp,
    float* __restrict__ Lp, int U)
{
    int b = blockIdx.z, h = blockIdx.y, c = blockIdx.x;
    int bh = b * Hc + h;
    int tid = threadIdx.x;
    int lane = tid & 63, g = tid >> 6;

    __shared__ float4 sK4[64][16];          // 16KB  row=key, col=lb^(key&7)
    __shared__ float4 sV4[64][16];          // 16KB  row=d, col=(key>>2)^(d&7)
    __shared__ unsigned short sQh[48][64];  // 6KB   bf16 scaled queries
    __shared__ float sP[48][64];            // 12KB  probs handoff
    __shared__ int sqi[48];

    if (tid < U) sqi[tid] = top[(size_t)bh * U + tid];
    __syncthreads();
    for (int u = g; u < U; u += 4)
        sQh[u][lane] = f2bf(Q[(((size_t)b * Lc + sqi[u]) * Hc + h) * Dc + lane] * 0.125f);

    int qbm = sqi[U - 1];                    // globally sorted -> max q
    // wave slot list: strided picks of a sorted array are sorted
    int uu[12], qq[12];
    #pragma unroll
    for (int i = 0; i < 12; i++) {
        int u = g + 4 * i;
        uu[i] = (u < U) ? u : (U - 1);
        qq[i] = sqi[uu[i]];
    }

    float m_r[12], lp_r[12], o_r[12];
    #pragma unroll
    for (int i = 0; i < 12; i++) { m_r[i] = -INFINITY; lp_r[i] = 0.f; o_r[i] = 0.f; }

    int k0c = c_cb[c], k1c = c_cb[c + 1];
    int ntile = 0;
    if (qbm >= k0c) ntile = (min(qbm, k1c - 1) - k0c) / 64 + 1;
    int kswz = lane & 7;

    float4 rk0, rk1, rk2, rk3, rv0, rv1, rv2, rv3;
#define PREFETCH(t) { int kk0_ = k0c + (t) * 64; \
    const float* kp_ = K + (((size_t)b * Lc + kk0_ + lane) * Hc + h) * Dc + g * 16; \
    const float* vp_ = V + (((size_t)b * Lc + kk0_ + lane) * Hc + h) * Dc + g * 16; \
    rk0 = *(const float4*)(kp_);      rk1 = *(const float4*)(kp_ + 4); \
    rk2 = *(const float4*)(kp_ + 8);  rk3 = *(const float4*)(kp_ + 12); \
    rv0 = *(const float4*)(vp_);      rv1 = *(const float4*)(vp_ + 4); \
    rv2 = *(const float4*)(vp_ + 8);  rv3 = *(const float4*)(vp_ + 12); }

    if (ntile > 0) PREFETCH(0)

    for (int t = 0; t < ntile; t++) {
        int k0 = k0c + t * 64;
        __syncthreads();   // previous tile consumed; sQh/sqi writes ordered
        {   // write staged regs -> LDS
            int base = g * 4;
            sK4[lane][(base + 0) ^ kswz] = rk0;
            sK4[lane][(base + 1) ^ kswz] = rk1;
            sK4[lane][(base + 2) ^ kswz] = rk2;
            sK4[lane][(base + 3) ^ kswz] = rk3;
            int d0 = base * 4;
            float4 vw;
#define VSCAT(rv, dd) vw = rv; \
            ((float*)&sV4[dd + 0][(lane >> 2) ^ ((dd + 0) & 7)])[lane & 3] = vw.x; \
            ((float*)&sV4[dd + 1][(lane >> 2) ^ ((dd + 1) & 7)])[lane & 3] = vw.y; \
            ((float*)&sV4[dd + 2][(lane >> 2) ^ ((dd + 2) & 7)])[lane & 3] = vw.z; \
            ((float*)&sV4[dd + 3][(lane >> 2) ^ ((dd + 3) & 7)])[lane & 3] = vw.w;
            VSCAT(rv0, d0) VSCAT(rv1, d0 + 4) VSCAT(rv2, d0 + 8) VSCAT(rv3, d0 + 12)
#undef VSCAT
        }
        if (t + 1 < ntile) PREFETCH(t + 1)   // overlaps compute below
        __syncthreads();

        #pragma unroll
        for (int j0 = 0; j0 < 12; j0 += 4) {
            if (k0 > qq[j0 + 3]) continue;   // sorted: group max
            const unsigned short* qA = sQh[uu[j0 + 0]];
            const unsigned short* qB = sQh[uu[j0 + 1]];
            const unsigned short* qC = sQh[uu[j0 + 2]];
            const unsigned short* qD = sQh[uu[j0 + 3]];
            // ---- QK^T: lane = key
            float s0 = 0.f, s1 = 0.f, s2 = 0.f, s3 = 0.f;
            #pragma unroll
            for (int lb = 0; lb < 16; lb++) {
                float4 kb = sK4[lane][lb ^ kswz];
                uint2 ra = *(const uint2*)(qA + lb * 4);
                uint2 rb = *(const uint2*)(qB + lb * 4);
                uint2 rc = *(const uint2*)(qC + lb * 4);
                uint2 rd = *(const uint2*)(qD + lb * 4);
                s0 += kb.x*bflo(ra.x) + kb.y*bfhi(ra.x) + kb.z*bflo(ra.y) + kb.w*bfhi(ra.y);
                s1 += kb.x*bflo(rb.x) + kb.y*bfhi(rb.x) + kb.z*bflo(rb.y) + kb.w*bfhi(rb.y);
                s2 += kb.x*bflo(rc.x) + kb.y*bfhi(rc.x) + kb.z*bflo(rc.y) + kb.w*bfhi(rc.y);
                s3 += kb.x*bflo(rd.x) + kb.y*bfhi(rd.x) + kb.z*bflo(rd.y) + kb.w*bfhi(rd.y);
            }
            // ---- defer-max online softmax; l accumulated per-lane
#define SLOT(jj, sv) { \
            float sA = (k0 + lane > qq[jj]) ? -INFINITY : sv; \
            if (__any(sA - m_r[jj] > 8.0f)) { \
                float tm = wmax64(sA); \
                float mnew = fmaxf(m_r[jj], tm); \
                float al = __expf(m_r[jj] - mnew); \
                m_r[jj] = mnew; lp_r[jj] *= al; o_r[jj] *= al; \
            } \
            float p = __expf(sA - m_r[jj]); \
            lp_r[jj] += p; \
            sP[uu[jj]][lane] = p; }
            SLOT(j0 + 0, s0)
            SLOT(j0 + 1, s1)
            SLOT(j0 + 2, s2)
            SLOT(j0 + 3, s3)
#undef SLOT
            // ---- PV: lane = d
            float p0 = 0.f, p1 = 0.f, p2 = 0.f, p3 = 0.f;
            #pragma unroll
            for (int kk = 0; kk < 16; kk++) {
                float4 vb = sV4[lane][kk ^ kswz];
                float4 wa = *(const float4*)&sP[uu[j0 + 0]][kk * 4];
                float4 wb = *(const float4*)&sP[uu[j0 + 1]][kk * 4];
                float4 wc = *(const float4*)&sP[uu[j0 + 2]][kk * 4];
                float4 wd = *(const float4*)&sP[uu[j0 + 3]][kk * 4];
                p0 += wa.x*vb.x + wa.y*vb.y + wa.z*vb.z + wa.w*vb.w;
                p1 += wb.x*vb.x + wb.y*vb.y + wb.z*vb.z + wb.w*vb.w;
                p2 += wc.x*vb.x + wc.y*vb.y + wc.z*vb.z + wc.w*vb.w;
                p3 += wd.x*vb.x + wd.y*vb.y + wd.z*vb.z + wd.w*vb.w;
            }
            o_r[j0 + 0] += p0;
            o_r[j0 + 1] += p1;
            o_r[j0 + 2] += p2;
            o_r[j0 + 3] += p3;
        }
    }
#undef PREFETCH

    // write partials (even ntile==0: combine's lv>0 guard filters).
    // duplicate slots write identical values to identical addresses.
    #pragma unroll
    for (int i = 0; i < 12; i++) {
        float lsum = wsum64(lp_r[i]);
        size_t s0_ = ((size_t)bh * NCH + c) * U + uu[i];
        Opart[s0_ * 64 + lane] = f2bf(o_r[i]);
        if (lane == 0) { Mp[s0_] = m_r[i]; Lp[s0_] = lsum; }
    }
}

// ---------------------------------------------------------------- kernel 5
__global__ __launch_bounds__(64) void k_combine(
    const unsigned short* __restrict__ Opart, const float* __restrict__ Mp,
    const float* __restrict__ Lp, const int* __restrict__ top,
    float* __restrict__ out, int U)
{
    int b = blockIdx.z, h = blockIdx.y, u = blockIdx.x;
    int bh = b * Hc + h;
    int lane = threadIdx.x;
    int q = top[(size_t)bh * U + u];

    float mv[NCH], lv[NCH];
    float mg = -INFINITY;
    #pragma unroll
    for (int c = 0; c < NCH; c++) {
        size_t s0 = ((size_t)bh * NCH + c) * U + u;
        mv[c] = Mp[s0]; lv[c] = Lp[s0];
        mg = fmaxf(mg, mv[c]);
    }
    float Ls = 0.f, o = 0.f;
    #pragma unroll
    for (int c = 0; c < NCH; c++) {
        if (lv[c] > 0.f) {
            float w = __expf(mv[c] - mg);
            Ls += w * lv[c];
            o  += w * bf2f(Opart[(((size_t)bh * NCH + c) * U + u) * 64 + lane]);
        }
    }
    out[(((size_t)b * Lc + q) * Hc + h) * Dc + lane] = o / Ls;
}

extern "C" void kernel_launch(void* const* d_in, const int* in_sizes, int n_in,
                              void* d_out, int out_size, void* d_ws, size_t ws_size,
                              hipStream_t stream)
{
    const float* Q = (const float*)d_in[0];
    const float* K = (const float*)d_in[1];
    const float* V = (const float*)d_in[2];
    const int* idx = (const int*)d_in[3];
    float* out = (float*)d_out;

    int S = in_sizes[3] / Lc;   // sample_k == u == 45

    // ws layout (bytes). M [0,1MB) dead after topk; Opart (bf16, 5.90MB)
    // reuses that region. Mp@6291456 (184KB), Lp@6553600 (184KB),
    // bsum@6815744 (256KB), top@8388608 (11.5KB).
    char* ws = (char*)d_ws;
    float* M              = (float*)ws;
    unsigned short* Opart = (unsigned short*)ws;
    float* Mp    = (float*)(ws + 6291456);
    float* Lp    = (float*)(ws + 6553600);
    float* bsum  = (float*)(ws + 6815744);
    int*   top   = (int*)  (ws + 8388608);

    dim3 blk(256);
    if (S == 45)
        k_meas_t<45><<<dim3(Lc / 4, Hc, Bc), blk, 0, stream>>>(Q, K, idx, M);
    else
        k_meas_dyn  <<<dim3(Lc / 4, Hc, Bc), blk, 0, stream>>>(Q, K, idx, M, S);
    k_topk   <<<dim3(Bc * Hc),        blk, 0, stream>>>(M, top, S);
    k_vsum   <<<dim3(VCH, Hc, Bc),    blk, 0, stream>>>(V, bsum);
    k_scan   <<<dim3(VCH, Hc, Bc),    blk, 0, stream>>>(V, bsum, out);
    k_attn2  <<<dim3(NCH, Hc, Bc),    blk, 0, stream>>>(Q, K, V, top, Opart, Mp, Lp, S);
    k_combine<<<dim3(S, Hc, Bc), dim3(64), 0, stream>>>(Opart, Mp, Lp, top, out, S);
}